// Round 7
// baseline (55.345 us; speedup 1.0000x reference)
//
#include <hip/hip_runtime.h>

#define N_NODES  100000
#define N_EDGES  3200000
#define D_FEAT   128
#define SLICE    33344         // 3 slices cover 100000; 130.25 KiB LDS
#define SLICE4   (SLICE / 4)
#define N_SLICES 3
#define NCHUNK   80            // edge chunks; grid = 240 = 10 groups of 24
#define EPB      40000         // N_EDGES / NCHUNK; multiple of EPT
#define EPT      16            // edges per thread per pipeline stage
#define VEC4     (EPT / 4)
#define TPB      1024
#define STRIDE   (TPB * EPT)   // 16384 edges per stage per block

__device__ __forceinline__ unsigned short f2bf(float f) {
    union { float f; unsigned u; } c; c.f = f;
    unsigned r = c.u + 0x7FFFu + ((c.u >> 16) & 1u);   // round-nearest-even
    return (unsigned short)(r >> 16);
}
__device__ __forceinline__ float bf2f(unsigned short h) {
    union { unsigned u; float f; } c; c.u = ((unsigned)h) << 16; return c.f;
}

// ---------------------------------------------------------------------------
// Kernel 1: per-node feature row-sum. 32 lanes per row, float4 per lane.
// ---------------------------------------------------------------------------
__global__ void __launch_bounds__(256) rowsum_kernel(
    const float* __restrict__ feat,
    float* __restrict__ rowsum)
{
    const int gid = (int)(blockIdx.x * blockDim.x + threadIdx.x);
    const int row = gid >> 5;
    const int sub = gid & 31;
    if (row >= N_NODES) return;

    const float4 v = reinterpret_cast<const float4*>(
        feat + (size_t)row * D_FEAT)[sub];
    float s = (v.x + v.y) + (v.z + v.w);

    #pragma unroll
    for (int off = 16; off > 0; off >>= 1)
        s += __shfl_xor(s, off, 64);

    if (sub == 0) rowsum[row] = s;
}

// ---------------------------------------------------------------------------
// Kernel 2: LDS-privatized scatter, 3-stage pipeline, EPT=16 (24 outstanding
// vmem instrs per wave), XCD-sibling swizzle. EPB is a multiple of EPT and
// chunks tile N_EDGES exactly, so one bool per 16-edge stage covers validity.
// All per-stage arrays are accessed only with compile-time indices
// (fully unrolled) so they stay in registers (rule #20).
// ---------------------------------------------------------------------------
struct Stage { int4 d[VEC4]; int4 s[VEC4]; };

__device__ __forceinline__ void load16(Stage& st,
                                       const int* __restrict__ ed,
                                       const int* __restrict__ es,
                                       int e, int end)
{
    if (e < end) {
        #pragma unroll
        for (int q = 0; q < VEC4; ++q) {
            st.d[q] = *reinterpret_cast<const int4*>(ed + e + q * 4);
            st.s[q] = *reinterpret_cast<const int4*>(es + e + q * 4);
        }
    }
}

__device__ __forceinline__ void gather16(const Stage& st, bool valid,
                                         int lo, unsigned len,
                                         const float* __restrict__ rowsum,
                                         unsigned* j, float* w)
{
    #pragma unroll
    for (int q = 0; q < VEC4; ++q) {
        const int dd[4] = { st.d[q].x, st.d[q].y, st.d[q].z, st.d[q].w };
        const int ss[4] = { st.s[q].x, st.s[q].y, st.s[q].z, st.s[q].w };
        #pragma unroll
        for (int t = 0; t < 4; ++t) {
            const unsigned jj = valid ? (unsigned)(dd[t] - lo) : 0xFFFFFFFFu;
            j[q * 4 + t] = jj;
            w[q * 4 + t] = (jj < len) ? rowsum[ss[t]] : 0.0f;
        }
    }
}

__global__ void __launch_bounds__(TPB, 4) scatter_kernel(
    const int* __restrict__ edge_src,
    const int* __restrict__ edge_dst,
    const float* __restrict__ rowsum,
    unsigned short* __restrict__ copies)
{
    __shared__ float lds[SLICE];

    const int tid  = (int)threadIdx.x;
    const int bid  = (int)blockIdx.x;
    const int g    = bid / 24;
    const int r    = bid % 24;
    const int xcd  = r & 7;
    const int s    = r >> 3;              // slice (tier)
    const int b    = g * 8 + xcd;         // chunk
    const int lo   = s * SLICE;
    const unsigned len = (unsigned)((N_NODES - lo < SLICE) ? (N_NODES - lo) : SLICE);

    float4 z; z.x = z.y = z.z = z.w = 0.0f;
    for (int i = tid; i < SLICE4; i += TPB)
        reinterpret_cast<float4*>(lds)[i] = z;
    __syncthreads();

    const int begin = b * EPB;
    const int end   = begin + EPB;        // chunks tile N_EDGES exactly

    int eA = begin + tid * EPT;           // stage being committed
    int eB = eA + STRIDE;                 // stage being gathered

    Stage stA, stB;
    load16(stA, edge_dst, edge_src, eA, end);
    load16(stB, edge_dst, edge_src, eB, end);

    unsigned jA[EPT]; float wA[EPT];
    gather16(stA, eA < end, lo, len, rowsum, jA, wA);

    while (eA < end) {
        // (1) issue idx loads for stage k+2
        const int eC = eB + STRIDE;
        Stage stC;
        load16(stC, edge_dst, edge_src, eC, end);

        // (2) issue gathers for stage k+1 (indices arrived one iter ago)
        unsigned jB[EPT]; float wB[EPT];
        gather16(stB, eB < end, lo, len, rowsum, jB, wB);

        // (3) commit stage k (gathers arrived one iter ago)
        #pragma unroll
        for (int k = 0; k < EPT; ++k)
            if (jA[k] < len) atomicAdd(&lds[jA[k]], wA[k]);

        // rotate stages
        eA = eB; eB = eC;
        stB = stC;
        #pragma unroll
        for (int k = 0; k < EPT; ++k) { jA[k] = jB[k]; wA[k] = wB[k]; }
    }
    __syncthreads();

    // flush LDS slice as bf16 partials
    unsigned short* __restrict__ dstp = copies + ((size_t)s * NCHUNK + b) * SLICE;
    const int len4 = (int)len >> 2;
    for (int i = tid; i < len4; i += TPB) {
        const float4 v = reinterpret_cast<const float4*>(lds)[i];
        ushort4 o;
        o.x = f2bf(v.x); o.y = f2bf(v.y); o.z = f2bf(v.z); o.w = f2bf(v.w);
        reinterpret_cast<ushort4*>(dstp)[i] = o;
    }
}

// ---------------------------------------------------------------------------
// Kernel 3: reduce the NCHUNK bf16 copies per slice + activations + int cast.
// ---------------------------------------------------------------------------
__global__ void __launch_bounds__(256) reduce_final_kernel(
    const unsigned short* __restrict__ copies,
    int* __restrict__ out)
{
    const int i4 = (int)(blockIdx.x * blockDim.x + threadIdx.x);
    if (i4 >= N_NODES / 4) return;

    const int s  = (i4 >= 2 * SLICE4) ? 2 : (i4 >= SLICE4 ? 1 : 0);
    const int j4 = i4 - s * SLICE4;

    float ax = 0.0f, ay = 0.0f, az = 0.0f, aw = 0.0f;
    const ushort4* base = reinterpret_cast<const ushort4*>(copies)
                        + (size_t)s * NCHUNK * SLICE4 + j4;
    #pragma unroll 4
    for (int c = 0; c < NCHUNK; ++c) {
        const ushort4 v = base[(size_t)c * SLICE4];
        ax += bf2f(v.x); ay += bf2f(v.y); az += bf2f(v.z); aw += bf2f(v.w);
    }

    auto act = [](float x) -> int {
        const float a1 = (x  > 0.0f) ? x  : 0.1f * x;
        const float r2 = 16.0f * a1;
        const float a2 = (r2 > 0.0f) ? r2 : 0.1f * r2;
        return (int)(10.0f * a2);
    };

    int4 o;
    o.x = act(ax); o.y = act(ay); o.z = act(az); o.w = act(aw);
    reinterpret_cast<int4*>(out)[i4] = o;
}

extern "C" void kernel_launch(void* const* d_in, const int* in_sizes, int n_in,
                              void* d_out, int out_size, void* d_ws, size_t ws_size,
                              hipStream_t stream)
{
    const float* feat     = (const float*)d_in[0];
    const int*   edge_src = (const int*)d_in[1];
    const int*   edge_dst = (const int*)d_in[2];
    int*         out      = (int*)d_out;

    float* rowsum = (float*)d_ws;                                  // N_NODES f32
    unsigned short* copies = (unsigned short*)(rowsum + N_NODES);  // 3*NCHUNK*SLICE bf16 (~16 MB)

    // Kernel 1: 32 threads per node
    {
        const int threads = 256;
        const long long total = (long long)N_NODES * 32;
        const int blocks = (int)((total + threads - 1) / threads);
        rowsum_kernel<<<blocks, threads, 0, stream>>>(feat, rowsum);
    }

    // Kernel 2: 240 blocks, XCD-sibling swizzled, EPT=16 pipeline
    scatter_kernel<<<N_SLICES * NCHUNK, TPB, 0, stream>>>(edge_src, edge_dst,
                                                          rowsum, copies);

    // Kernel 3: fused reduce + activations + int cast
    {
        const int threads = 256;
        const int blocks = (N_NODES / 4 + threads - 1) / threads;
        reduce_final_kernel<<<blocks, threads, 0, stream>>>(copies, out);
    }
}

// Round 8
// 52.169 us; speedup vs baseline: 1.0609x; 1.0609x over previous
//
#include <hip/hip_runtime.h>

#define N_NODES  100000
#define N_EDGES  3200000
#define D_FEAT   128
#define SLICE    20000         // 5 slices tile 100000 exactly; 78.125 KiB LDS
#define SLICE4   (SLICE / 4)   // 5000
#define N_SLICES 5
#define NCHUNK   80            // edge chunks; grid = 400 = 10 groups of 40
#define EPB      40000         // N_EDGES / NCHUNK; multiple of EPT
#define EPT      8             // edges per thread per iteration (r4 shape)
#define TPB      1024
#define STRIDE   (TPB * EPT)   // 8192 edges per iteration per block

__device__ __forceinline__ unsigned short f2bf(float f) {
    union { float f; unsigned u; } c; c.f = f;
    unsigned r = c.u + 0x7FFFu + ((c.u >> 16) & 1u);   // round-nearest-even
    return (unsigned short)(r >> 16);
}
__device__ __forceinline__ float bf2f(unsigned short h) {
    union { unsigned u; float f; } c; c.u = ((unsigned)h) << 16; return c.f;
}

// ---------------------------------------------------------------------------
// Kernel 1: per-node feature row-sum. 32 lanes per row, float4 per lane.
// ---------------------------------------------------------------------------
__global__ void __launch_bounds__(256) rowsum_kernel(
    const float* __restrict__ feat,
    float* __restrict__ rowsum)
{
    const int gid = (int)(blockIdx.x * blockDim.x + threadIdx.x);
    const int row = gid >> 5;
    const int sub = gid & 31;
    if (row >= N_NODES) return;

    const float4 v = reinterpret_cast<const float4*>(
        feat + (size_t)row * D_FEAT)[sub];
    float s = (v.x + v.y) + (v.z + v.w);

    #pragma unroll
    for (int off = 16; off > 0; off >>= 1)
        s += __shfl_xor(s, off, 64);

    if (sub == 0) rowsum[row] = s;
}

// ---------------------------------------------------------------------------
// Kernel 2: LDS-privatized scatter, 5 slices (78 KiB LDS) -> 2 blocks/CU =
// 8 waves/SIMD (TLP x2 vs the 3-slice/130KiB version). __launch_bounds__
// (1024, 8) forces <=64 VGPR so the occupancy tier is actually reached.
// 2-stage pipeline, EPT=8 (the best-measured ILP depth). XCD-sibling
// swizzle: the 5 tiers of a chunk share one XCD's L2.
// Since 5*SLICE == N_NODES exactly, len == SLICE (compile-time).
// ---------------------------------------------------------------------------
__global__ void __launch_bounds__(TPB, 8) scatter_kernel(
    const int* __restrict__ edge_src,
    const int* __restrict__ edge_dst,
    const float* __restrict__ rowsum,
    unsigned short* __restrict__ copies)
{
    __shared__ float lds[SLICE];

    const int tid = (int)threadIdx.x;
    const int bid = (int)blockIdx.x;
    const int g   = bid / 40;
    const int r   = bid % 40;
    const int xcd = r & 7;
    const int s   = r >> 3;               // tier / slice (0..4)
    const int b   = g * 8 + xcd;          // chunk (0..79)
    const int lo  = s * SLICE;

    float4 z; z.x = z.y = z.z = z.w = 0.0f;
    for (int i = tid; i < SLICE4; i += TPB)
        reinterpret_cast<float4*>(lds)[i] = z;
    __syncthreads();

    const int begin = b * EPB;
    const int end   = begin + EPB;        // chunks tile N_EDGES exactly

    // EPB % EPT == 0 and e is EPT-aligned within the chunk, so one bool
    // covers a whole 8-edge group.
    int e = begin + tid * EPT;
    bool v = (e < end);

    int4 d0, d1, s0, s1;
    if (v) {
        d0 = *(const int4*)(edge_dst + e);     s0 = *(const int4*)(edge_src + e);
        d1 = *(const int4*)(edge_dst + e + 4); s1 = *(const int4*)(edge_src + e + 4);
    }

    while (v) {
        // prefetch next iteration's indices
        const int en = e + STRIDE;
        const bool vn = (en < end);
        int4 nd0, nd1, ns0, ns1;
        if (vn) {
            nd0 = *(const int4*)(edge_dst + en);     ns0 = *(const int4*)(edge_src + en);
            nd1 = *(const int4*)(edge_dst + en + 4); ns1 = *(const int4*)(edge_src + en + 4);
        }

        // gather (predicated on slice membership)
        const unsigned j0 = (unsigned)(d0.x - lo);
        const unsigned j1 = (unsigned)(d0.y - lo);
        const unsigned j2 = (unsigned)(d0.z - lo);
        const unsigned j3 = (unsigned)(d0.w - lo);
        const unsigned j4 = (unsigned)(d1.x - lo);
        const unsigned j5 = (unsigned)(d1.y - lo);
        const unsigned j6 = (unsigned)(d1.z - lo);
        const unsigned j7 = (unsigned)(d1.w - lo);

        float w0 = (j0 < SLICE) ? rowsum[s0.x] : 0.0f;
        float w1 = (j1 < SLICE) ? rowsum[s0.y] : 0.0f;
        float w2 = (j2 < SLICE) ? rowsum[s0.z] : 0.0f;
        float w3 = (j3 < SLICE) ? rowsum[s0.w] : 0.0f;
        float w4 = (j4 < SLICE) ? rowsum[s1.x] : 0.0f;
        float w5 = (j5 < SLICE) ? rowsum[s1.y] : 0.0f;
        float w6 = (j6 < SLICE) ? rowsum[s1.z] : 0.0f;
        float w7 = (j7 < SLICE) ? rowsum[s1.w] : 0.0f;

        // commit
        if (j0 < SLICE) atomicAdd(&lds[j0], w0);
        if (j1 < SLICE) atomicAdd(&lds[j1], w1);
        if (j2 < SLICE) atomicAdd(&lds[j2], w2);
        if (j3 < SLICE) atomicAdd(&lds[j3], w3);
        if (j4 < SLICE) atomicAdd(&lds[j4], w4);
        if (j5 < SLICE) atomicAdd(&lds[j5], w5);
        if (j6 < SLICE) atomicAdd(&lds[j6], w6);
        if (j7 < SLICE) atomicAdd(&lds[j7], w7);

        e = en; v = vn;
        d0 = nd0; d1 = nd1; s0 = ns0; s1 = ns1;
    }
    __syncthreads();

    // flush LDS slice as bf16 partials
    unsigned short* __restrict__ dstp = copies + ((size_t)s * NCHUNK + b) * SLICE;
    for (int i = tid; i < SLICE4; i += TPB) {
        const float4 vv = reinterpret_cast<const float4*>(lds)[i];
        ushort4 o;
        o.x = f2bf(vv.x); o.y = f2bf(vv.y); o.z = f2bf(vv.z); o.w = f2bf(vv.w);
        reinterpret_cast<ushort4*>(dstp)[i] = o;
    }
}

// ---------------------------------------------------------------------------
// Kernel 3: reduce the NCHUNK bf16 copies per slice + activations + int cast.
// ---------------------------------------------------------------------------
__global__ void __launch_bounds__(256) reduce_final_kernel(
    const unsigned short* __restrict__ copies,
    int* __restrict__ out)
{
    const int i4 = (int)(blockIdx.x * blockDim.x + threadIdx.x);
    if (i4 >= N_NODES / 4) return;

    const int s  = i4 / SLICE4;            // tier
    const int j4 = i4 - s * SLICE4;

    float ax = 0.0f, ay = 0.0f, az = 0.0f, aw = 0.0f;
    const ushort4* base = reinterpret_cast<const ushort4*>(copies)
                        + (size_t)s * NCHUNK * SLICE4 + j4;
    #pragma unroll 4
    for (int c = 0; c < NCHUNK; ++c) {
        const ushort4 v = base[(size_t)c * SLICE4];
        ax += bf2f(v.x); ay += bf2f(v.y); az += bf2f(v.z); aw += bf2f(v.w);
    }

    auto act = [](float x) -> int {
        const float a1 = (x  > 0.0f) ? x  : 0.1f * x;
        const float r2 = 16.0f * a1;
        const float a2 = (r2 > 0.0f) ? r2 : 0.1f * r2;
        return (int)(10.0f * a2);
    };

    int4 o;
    o.x = act(ax); o.y = act(ay); o.z = act(az); o.w = act(aw);
    reinterpret_cast<int4*>(out)[i4] = o;
}

extern "C" void kernel_launch(void* const* d_in, const int* in_sizes, int n_in,
                              void* d_out, int out_size, void* d_ws, size_t ws_size,
                              hipStream_t stream)
{
    const float* feat     = (const float*)d_in[0];
    const int*   edge_src = (const int*)d_in[1];
    const int*   edge_dst = (const int*)d_in[2];
    int*         out      = (int*)d_out;

    float* rowsum = (float*)d_ws;                                  // N_NODES f32
    unsigned short* copies = (unsigned short*)(rowsum + N_NODES);  // 5*NCHUNK*SLICE bf16 (16 MB)

    // Kernel 1: 32 threads per node
    {
        const int threads = 256;
        const long long total = (long long)N_NODES * 32;
        const int blocks = (int)((total + threads - 1) / threads);
        rowsum_kernel<<<blocks, threads, 0, stream>>>(feat, rowsum);
    }

    // Kernel 2: 400 blocks (2/CU), XCD-sibling swizzled, 8 waves/SIMD
    scatter_kernel<<<N_SLICES * NCHUNK, TPB, 0, stream>>>(edge_src, edge_dst,
                                                          rowsum, copies);

    // Kernel 3: fused reduce + activations + int cast
    {
        const int threads = 256;
        const int blocks = (N_NODES / 4 + threads - 1) / threads;
        reduce_final_kernel<<<blocks, threads, 0, stream>>>(copies, out);
    }
}